// Round 4
// baseline (3010.156 us; speedup 1.0000x reference)
//
#include <hip/hip_runtime.h>
#include <math.h>

#define DIM 128
#define NHEADS 4

// ---------------------------------------------------------------------------
// K1: h_src = x @ W_src, h_dst = x @ W_dst   (fused; 8 x-rows per block)
// threads 0..127 -> W_src cols, threads 128..255 -> W_dst cols
// ---------------------------------------------------------------------------
__global__ __launch_bounds__(256) void k_dual_gemm(
    const float* __restrict__ x,
    const float* __restrict__ Wsrc, const float* __restrict__ Wdst,
    float* __restrict__ h_src, float* __restrict__ h_dst, int n)
{
    __shared__ float xs[8][DIM];
    const int tid = threadIdx.x;
    const int r0 = blockIdx.x * 8;
    {
        int r  = tid >> 5;     // row 0..7
        int c4 = tid & 31;     // float4 index within row
        int row = r0 + r;
        float4 v = make_float4(0.f, 0.f, 0.f, 0.f);
        if (row < n) v = ((const float4*)(x + (size_t)row * DIM))[c4];
        ((float4*)xs[r])[c4] = v;
    }
    __syncthreads();

    const int c = tid & 127;
    const float* __restrict__ W = (tid < 128) ? Wsrc : Wdst;
    float* __restrict__ H       = (tid < 128) ? h_src : h_dst;

    float acc[8] = {0.f, 0.f, 0.f, 0.f, 0.f, 0.f, 0.f, 0.f};
    #pragma unroll
    for (int j = 0; j < DIM; ++j) {
        float w = W[j * DIM + c];
        #pragma unroll
        for (int r = 0; r < 8; ++r) acc[r] += xs[r][j] * w;
    }
    #pragma unroll
    for (int r = 0; r < 8; ++r) {
        if (r0 + r < n) H[(size_t)(r0 + r) * DIM + c] = acc[r];
    }
}

// ---------------------------------------------------------------------------
// K2: edge pass. 32 lanes per edge (4 features/lane as float4).
//   a      = leaky_relu(h_src[s] + h_dst[d], 0.2)
//   alpha  = a @ W_attn            (4 heads; cross-lane shfl reduce)
//   aexp   = exp(alpha)            (global-max shift cancels analytically;
//            alpha std ~0.35, max ~2 -> fp32 exp safe, 1e-9 term negligible)
//   denom[d][h] += aexp[h]                         (4 atomics)
//   numer[d][f] += aexp[head(f)] * h_src[s][f]     (128 atomics)
// ---------------------------------------------------------------------------
__global__ __launch_bounds__(256) void k_edge(
    const int* __restrict__ ei,
    const float* __restrict__ h_src, const float* __restrict__ h_dst,
    const float* __restrict__ W_attn,
    float* __restrict__ numer, float* __restrict__ denom, int E)
{
    const int e = blockIdx.x * 8 + (threadIdx.x >> 5);
    if (e >= E) return;
    const int lane = threadIdx.x & 31;

    const int s = ei[e];
    const int d = ei[E + e];

    const float4 hs = ((const float4*)(h_src + (size_t)s * DIM))[lane];
    const float4 hd = ((const float4*)(h_dst + (size_t)d * DIM))[lane];

    float a0 = hs.x + hd.x; a0 = a0 > 0.f ? a0 : 0.2f * a0;
    float a1 = hs.y + hd.y; a1 = a1 > 0.f ? a1 : 0.2f * a1;
    float a2 = hs.z + hd.z; a2 = a2 > 0.f ? a2 : 0.2f * a2;
    float a3 = hs.w + hd.w; a3 = a3 > 0.f ? a3 : 0.2f * a3;

    const int f = lane * 4;  // this lane's first feature row in W_attn [128][4]
    const float4 w0 = ((const float4*)W_attn)[f + 0];
    const float4 w1 = ((const float4*)W_attn)[f + 1];
    const float4 w2 = ((const float4*)W_attn)[f + 2];
    const float4 w3 = ((const float4*)W_attn)[f + 3];

    float px = a0 * w0.x + a1 * w1.x + a2 * w2.x + a3 * w3.x;
    float py = a0 * w0.y + a1 * w1.y + a2 * w2.y + a3 * w3.y;
    float pz = a0 * w0.z + a1 * w1.z + a2 * w2.z + a3 * w3.z;
    float pw = a0 * w0.w + a1 * w1.w + a2 * w2.w + a3 * w3.w;

    #pragma unroll
    for (int m = 16; m > 0; m >>= 1) {
        px += __shfl_xor(px, m, 32);
        py += __shfl_xor(py, m, 32);
        pz += __shfl_xor(pz, m, 32);
        pw += __shfl_xor(pw, m, 32);
    }

    const float ex = __expf(px);
    const float ey = __expf(py);
    const float ez = __expf(pz);
    const float ew = __expf(pw);

    if (lane < 4) {
        float v = (lane == 0) ? ex : (lane == 1) ? ey : (lane == 2) ? ez : ew;
        atomicAdd(&denom[(size_t)d * NHEADS + lane], v);
    }

    const int head = lane >> 3;  // features lane*4..lane*4+3 all in head lane/8
    const float ah = (head == 0) ? ex : (head == 1) ? ey : (head == 2) ? ez : ew;

    float* np_ = numer + (size_t)d * DIM + f;
    atomicAdd(np_ + 0, ah * hs.x);
    atomicAdd(np_ + 1, ah * hs.y);
    atomicAdd(np_ + 2, ah * hs.z);
    atomicAdd(np_ + 3, ah * hs.w);
}

// ---------------------------------------------------------------------------
// K3: per-node finalize: out = numer/(denom+1e-9) + h_dst, then LayerNorm.
// One wave (64 lanes) per node, 2 features per lane.
// ---------------------------------------------------------------------------
__global__ __launch_bounds__(256) void k_node(
    const float* __restrict__ numer, const float* __restrict__ denom,
    const float* __restrict__ h_dst,
    const float* __restrict__ gamma, const float* __restrict__ beta,
    float* __restrict__ out, int n)
{
    const int node = blockIdx.x * 4 + (threadIdx.x >> 6);
    if (node >= n) return;
    const int lane = threadIdx.x & 63;

    const float2 nm = ((const float2*)(numer + (size_t)node * DIM))[lane];
    const float2 hd = ((const float2*)(h_dst + (size_t)node * DIM))[lane];
    const int h = lane >> 4;  // head of features {2*lane, 2*lane+1}
    const float den = denom[(size_t)node * NHEADS + h] + 1e-9f;

    const float o0 = nm.x / den + hd.x;
    const float o1 = nm.y / den + hd.y;

    float sum = o0 + o1;
    float sq  = o0 * o0 + o1 * o1;
    #pragma unroll
    for (int m = 32; m > 0; m >>= 1) {
        sum += __shfl_xor(sum, m, 64);
        sq  += __shfl_xor(sq,  m, 64);
    }
    const float mu   = sum * (1.0f / 128.0f);
    const float var  = sq * (1.0f / 128.0f) - mu * mu;
    const float rstd = rsqrtf(var + 1e-5f);

    const float2 g = ((const float2*)gamma)[lane];
    const float2 b = ((const float2*)beta)[lane];
    float2 res;
    res.x = (o0 - mu) * rstd * g.x + b.x;
    res.y = (o1 - mu) * rstd * g.y + b.y;
    ((float2*)(out + (size_t)node * DIM))[lane] = res;
}

// ---------------------------------------------------------------------------
extern "C" void kernel_launch(void* const* d_in, const int* in_sizes, int n_in,
                              void* d_out, int out_size, void* d_ws, size_t ws_size,
                              hipStream_t stream)
{
    const float* x     = (const float*)d_in[0];
    const int*   ei    = (const int*)d_in[1];
    const float* Wsrc  = (const float*)d_in[2];
    const float* Wdst  = (const float*)d_in[3];
    const float* Wattn = (const float*)d_in[4];
    const float* gamma = (const float*)d_in[5];
    const float* beta  = (const float*)d_in[6];
    float* out = (float*)d_out;

    const int n = in_sizes[0] / DIM;
    const int E = in_sizes[1] / 2;

    float* h_src = (float*)d_ws;                       // n*128
    float* h_dst = h_src + (size_t)n * DIM;            // n*128
    float* numer = h_dst + (size_t)n * DIM;            // n*128
    float* denom = numer + (size_t)n * DIM;            // n*4

    // zero the accumulators (ws is poisoned 0xAA before every launch)
    hipMemsetAsync(numer, 0, ((size_t)n * DIM + (size_t)n * NHEADS) * sizeof(float), stream);

    k_dual_gemm<<<(n + 7) / 8, 256, 0, stream>>>(x, Wsrc, Wdst, h_src, h_dst, n);
    k_edge<<<(E + 7) / 8, 256, 0, stream>>>(ei, h_src, h_dst, Wattn, numer, denom, E);
    k_node<<<(n + 3) / 4, 256, 0, stream>>>(numer, denom, h_dst, gamma, beta, out, n);
}

// Round 6
// 1556.305 us; speedup vs baseline: 1.9342x; 1.9342x over previous
//
#include <hip/hip_runtime.h>
#include <math.h>

#define DIM 128
#define NHEADS 4

// ---------------------------------------------------------------------------
// K1: h_src = x @ W_src, h_dst = x @ W_dst   (fused; 8 x-rows per block)
// threads 0..127 -> W_src cols, threads 128..255 -> W_dst cols
// NOTE: unroll capped at 8 — full unroll (round 4) hoisted ~128 W-loads,
// VGPR=256 + massive scratch spill (WRITE_SIZE 3.4 GB vs 51 MB ideal).
// ---------------------------------------------------------------------------
__global__ __launch_bounds__(256) void k_dual_gemm(
    const float* __restrict__ x,
    const float* __restrict__ Wsrc, const float* __restrict__ Wdst,
    float* __restrict__ h_src, float* __restrict__ h_dst, int n)
{
    __shared__ float xs[8][DIM];
    const int tid = threadIdx.x;
    const int r0 = blockIdx.x * 8;
    {
        int r  = tid >> 5;     // row 0..7
        int c4 = tid & 31;     // float4 index within row
        int row = r0 + r;
        float4 v = make_float4(0.f, 0.f, 0.f, 0.f);
        if (row < n) v = ((const float4*)(x + (size_t)row * DIM))[c4];
        ((float4*)xs[r])[c4] = v;
    }
    __syncthreads();

    const int c = tid & 127;
    const float* __restrict__ W = (tid < 128) ? Wsrc : Wdst;
    float* __restrict__ H       = (tid < 128) ? h_src : h_dst;

    float acc[8] = {0.f, 0.f, 0.f, 0.f, 0.f, 0.f, 0.f, 0.f};
    #pragma unroll 8
    for (int j = 0; j < DIM; ++j) {
        float w = W[j * DIM + c];
        #pragma unroll
        for (int r = 0; r < 8; ++r) acc[r] += xs[r][j] * w;
    }
    #pragma unroll
    for (int r = 0; r < 8; ++r) {
        if (r0 + r < n) H[(size_t)(r0 + r) * DIM + c] = acc[r];
    }
}

// ---------------------------------------------------------------------------
// K2: edge pass. 32 lanes per edge (4 features/lane as float4).
//   a      = leaky_relu(h_src[s] + h_dst[d], 0.2)
//   alpha  = a @ W_attn            (4 heads; cross-lane shfl reduce)
//   aexp   = exp(alpha)            (global-max shift cancels analytically;
//            alpha std ~0.35, max ~2 -> fp32 exp safe, 1e-9 term negligible)
//   denom[d][h] += aexp[h]                         (4 atomics)
//   numer[d][f] += aexp[head(f)] * h_src[s][f]     (128 atomics)
// ---------------------------------------------------------------------------
__global__ __launch_bounds__(256) void k_edge(
    const int* __restrict__ ei,
    const float* __restrict__ h_src, const float* __restrict__ h_dst,
    const float* __restrict__ W_attn,
    float* __restrict__ numer, float* __restrict__ denom, int E)
{
    const int e = blockIdx.x * 8 + (threadIdx.x >> 5);
    if (e >= E) return;
    const int lane = threadIdx.x & 31;

    const int s = ei[e];
    const int d = ei[E + e];

    const float4 hs = ((const float4*)(h_src + (size_t)s * DIM))[lane];
    const float4 hd = ((const float4*)(h_dst + (size_t)d * DIM))[lane];

    float a0 = hs.x + hd.x; a0 = a0 > 0.f ? a0 : 0.2f * a0;
    float a1 = hs.y + hd.y; a1 = a1 > 0.f ? a1 : 0.2f * a1;
    float a2 = hs.z + hd.z; a2 = a2 > 0.f ? a2 : 0.2f * a2;
    float a3 = hs.w + hd.w; a3 = a3 > 0.f ? a3 : 0.2f * a3;

    const int f = lane * 4;  // this lane's first feature row in W_attn [128][4]
    const float4 w0 = ((const float4*)W_attn)[f + 0];
    const float4 w1 = ((const float4*)W_attn)[f + 1];
    const float4 w2 = ((const float4*)W_attn)[f + 2];
    const float4 w3 = ((const float4*)W_attn)[f + 3];

    float px = a0 * w0.x + a1 * w1.x + a2 * w2.x + a3 * w3.x;
    float py = a0 * w0.y + a1 * w1.y + a2 * w2.y + a3 * w3.y;
    float pz = a0 * w0.z + a1 * w1.z + a2 * w2.z + a3 * w3.z;
    float pw = a0 * w0.w + a1 * w1.w + a2 * w2.w + a3 * w3.w;

    #pragma unroll
    for (int m = 16; m > 0; m >>= 1) {
        px += __shfl_xor(px, m, 32);
        py += __shfl_xor(py, m, 32);
        pz += __shfl_xor(pz, m, 32);
        pw += __shfl_xor(pw, m, 32);
    }

    const float ex = __expf(px);
    const float ey = __expf(py);
    const float ez = __expf(pz);
    const float ew = __expf(pw);

    if (lane < 4) {
        float v = (lane == 0) ? ex : (lane == 1) ? ey : (lane == 2) ? ez : ew;
        atomicAdd(&denom[(size_t)d * NHEADS + lane], v);
    }

    const int head = lane >> 3;  // features lane*4..lane*4+3 all in head lane/8
    const float ah = (head == 0) ? ex : (head == 1) ? ey : (head == 2) ? ez : ew;

    float* np_ = numer + (size_t)d * DIM + f;
    atomicAdd(np_ + 0, ah * hs.x);
    atomicAdd(np_ + 1, ah * hs.y);
    atomicAdd(np_ + 2, ah * hs.z);
    atomicAdd(np_ + 3, ah * hs.w);
}

// ---------------------------------------------------------------------------
// K3: per-node finalize: out = numer/(denom+1e-9) + h_dst, then LayerNorm.
// One wave (64 lanes) per node, 2 features per lane.
// ---------------------------------------------------------------------------
__global__ __launch_bounds__(256) void k_node(
    const float* __restrict__ numer, const float* __restrict__ denom,
    const float* __restrict__ h_dst,
    const float* __restrict__ gamma, const float* __restrict__ beta,
    float* __restrict__ out, int n)
{
    const int node = blockIdx.x * 4 + (threadIdx.x >> 6);
    if (node >= n) return;
    const int lane = threadIdx.x & 63;

    const float2 nm = ((const float2*)(numer + (size_t)node * DIM))[lane];
    const float2 hd = ((const float2*)(h_dst + (size_t)node * DIM))[lane];
    const int h = lane >> 4;  // head of features {2*lane, 2*lane+1}
    const float den = denom[(size_t)node * NHEADS + h] + 1e-9f;

    const float o0 = nm.x / den + hd.x;
    const float o1 = nm.y / den + hd.y;

    float sum = o0 + o1;
    float sq  = o0 * o0 + o1 * o1;
    #pragma unroll
    for (int m = 32; m > 0; m >>= 1) {
        sum += __shfl_xor(sum, m, 64);
        sq  += __shfl_xor(sq,  m, 64);
    }
    const float mu   = sum * (1.0f / 128.0f);
    const float var  = sq * (1.0f / 128.0f) - mu * mu;
    const float rstd = rsqrtf(var + 1e-5f);

    const float2 g = ((const float2*)gamma)[lane];
    const float2 b = ((const float2*)beta)[lane];
    float2 res;
    res.x = (o0 - mu) * rstd * g.x + b.x;
    res.y = (o1 - mu) * rstd * g.y + b.y;
    ((float2*)(out + (size_t)node * DIM))[lane] = res;
}

// ---------------------------------------------------------------------------
extern "C" void kernel_launch(void* const* d_in, const int* in_sizes, int n_in,
                              void* d_out, int out_size, void* d_ws, size_t ws_size,
                              hipStream_t stream)
{
    const float* x     = (const float*)d_in[0];
    const int*   ei    = (const int*)d_in[1];
    const float* Wsrc  = (const float*)d_in[2];
    const float* Wdst  = (const float*)d_in[3];
    const float* Wattn = (const float*)d_in[4];
    const float* gamma = (const float*)d_in[5];
    const float* beta  = (const float*)d_in[6];
    float* out = (float*)d_out;

    const int n = in_sizes[0] / DIM;
    const int E = in_sizes[1] / 2;

    float* h_src = (float*)d_ws;                       // n*128
    float* h_dst = h_src + (size_t)n * DIM;            // n*128
    float* numer = h_dst + (size_t)n * DIM;            // n*128
    float* denom = numer + (size_t)n * DIM;            // n*4

    // zero the accumulators (ws is poisoned 0xAA before every launch)
    hipMemsetAsync(numer, 0, ((size_t)n * DIM + (size_t)n * NHEADS) * sizeof(float), stream);

    k_dual_gemm<<<(n + 7) / 8, 256, 0, stream>>>(x, Wsrc, Wdst, h_src, h_dst, n);
    k_edge<<<(E + 7) / 8, 256, 0, stream>>>(ei, h_src, h_dst, Wattn, numer, denom, E);
    k_node<<<(n + 3) / 4, 256, 0, stream>>>(numer, denom, h_dst, gamma, beta, out, n);
}

// Round 12
// 435.791 us; speedup vs baseline: 6.9073x; 3.5712x over previous
//
#include <hip/hip_runtime.h>
#include <math.h>

#define DIM 128
#define NHEADS 4

// ---------------------------------------------------------------------------
// K1: h_src = x @ W_src, h_dst = x @ W_dst   (fused; 8 x-rows per block)
// unroll capped at 8 — full unroll spilled (VGPR=256, 3.4 GB scratch writes).
// ---------------------------------------------------------------------------
__global__ __launch_bounds__(256) void k_dual_gemm(
    const float* __restrict__ x,
    const float* __restrict__ Wsrc, const float* __restrict__ Wdst,
    float* __restrict__ h_src, float* __restrict__ h_dst, int n)
{
    __shared__ float xs[8][DIM];
    const int tid = threadIdx.x;
    const int r0 = blockIdx.x * 8;
    {
        int r  = tid >> 5;
        int c4 = tid & 31;
        int row = r0 + r;
        float4 v = make_float4(0.f, 0.f, 0.f, 0.f);
        if (row < n) v = ((const float4*)(x + (size_t)row * DIM))[c4];
        ((float4*)xs[r])[c4] = v;
    }
    __syncthreads();

    const int c = tid & 127;
    const float* __restrict__ W = (tid < 128) ? Wsrc : Wdst;
    float* __restrict__ H       = (tid < 128) ? h_src : h_dst;

    float acc[8] = {0.f, 0.f, 0.f, 0.f, 0.f, 0.f, 0.f, 0.f};
    #pragma unroll 8
    for (int j = 0; j < DIM; ++j) {
        float w = W[j * DIM + c];
        #pragma unroll
        for (int r = 0; r < 8; ++r) acc[r] += xs[r][j] * w;
    }
    #pragma unroll
    for (int r = 0; r < 8; ++r) {
        if (r0 + r < n) H[(size_t)(r0 + r) * DIM + c] = acc[r];
    }
}

// ---------------------------------------------------------------------------
// CSR build: histogram -> exclusive scan -> scatter (edge -> dst-grouped srcs)
// ---------------------------------------------------------------------------
__global__ __launch_bounds__(256) void k_hist(
    const int* __restrict__ ei, int* __restrict__ deg, int E)
{
    int e = blockIdx.x * 256 + threadIdx.x;
    if (e < E) atomicAdd(&deg[ei[E + e]], 1);
}

// single-block Hillis-Steele scan over n bins (n ~ 50K -> ~49 chunks of 1024)
__global__ __launch_bounds__(1024) void k_scan(
    const int* __restrict__ deg, int* __restrict__ offs, int n)
{
    __shared__ int buf[1024];
    __shared__ int carry_s;
    const int tid = threadIdx.x;
    if (tid == 0) carry_s = 0;
    __syncthreads();
    for (int base = 0; base < n; base += 1024) {
        int i = base + tid;
        int v = (i < n) ? deg[i] : 0;
        buf[tid] = v;
        __syncthreads();
        #pragma unroll
        for (int off = 1; off < 1024; off <<= 1) {
            int t = (tid >= off) ? buf[tid - off] : 0;
            __syncthreads();
            buf[tid] += t;
            __syncthreads();
        }
        int carry = carry_s;
        if (i < n) offs[i] = carry + buf[tid] - v;   // exclusive
        __syncthreads();
        if (tid == 1023) carry_s = carry + buf[1023];
        __syncthreads();
    }
    if (tid == 0) offs[n] = carry_s;
}

__global__ __launch_bounds__(256) void k_scatter(
    const int* __restrict__ ei, int* __restrict__ cursor,
    int* __restrict__ srcs, int E)
{
    int e = blockIdx.x * 256 + threadIdx.x;
    if (e >= E) return;
    int s = ei[e];
    int d = ei[E + e];
    int pos = atomicAdd(&cursor[d], 1);
    srcs[pos] = s;
}

// ---------------------------------------------------------------------------
// K2: pull-mode aggregation + residual + LayerNorm. One wave (64 lanes) per
// node; the two 32-lane halves process alternating edges. Lane l (0..31)
// owns features 4l..4l+3 (float4). ATTENTION DOT (round-11 bugfix): every
// lane computes partials for ALL 4 heads against full W_attn rows, then a
// width-32 butterfly produces the full 128-feature alpha per head (the
// width-8 variant summed only 32 features/head -> absmax 0.5 FAIL).
// ---------------------------------------------------------------------------
__global__ __launch_bounds__(256) void k_aggregate(
    const int* __restrict__ offs, const int* __restrict__ srcs,
    const float* __restrict__ h_src, const float* __restrict__ h_dst,
    const float* __restrict__ W_attn,
    const float* __restrict__ gamma, const float* __restrict__ beta,
    float* __restrict__ out, int n)
{
    const int node = blockIdx.x * 4 + (threadIdx.x >> 6);
    if (node >= n) return;
    const int lane = threadIdx.x & 63;
    const int half = lane >> 5;       // 0: even edges, 1: odd edges
    const int l    = lane & 31;       // float4 index within the row
    const int head = l >> 3;          // head of features 4l..4l+3

    const float4 hd = ((const float4*)(h_dst + (size_t)node * DIM))[l];

    // full W_attn rows 4l..4l+3 (all 4 head columns), row-major [128][4]
    const float4 w0 = ((const float4*)W_attn)[4 * l + 0];
    const float4 w1 = ((const float4*)W_attn)[4 * l + 1];
    const float4 w2 = ((const float4*)W_attn)[4 * l + 2];
    const float4 w3 = ((const float4*)W_attn)[4 * l + 3];

    const int beg = offs[node];
    const int end = offs[node + 1];

    float4 acc = make_float4(0.f, 0.f, 0.f, 0.f);
    float  den = 0.f;

    for (int j = beg + half; j < end; j += 2) {
        const int s = srcs[j];
        const float4 hs = ((const float4*)(h_src + (size_t)s * DIM))[l];

        float a0 = hs.x + hd.x; a0 = a0 > 0.f ? a0 : 0.2f * a0;
        float a1 = hs.y + hd.y; a1 = a1 > 0.f ? a1 : 0.2f * a1;
        float a2 = hs.z + hd.z; a2 = a2 > 0.f ? a2 : 0.2f * a2;
        float a3 = hs.w + hd.w; a3 = a3 > 0.f ? a3 : 0.2f * a3;

        float px = a0 * w0.x + a1 * w1.x + a2 * w2.x + a3 * w3.x;
        float py = a0 * w0.y + a1 * w1.y + a2 * w2.y + a3 * w3.y;
        float pz = a0 * w0.z + a1 * w1.z + a2 * w2.z + a3 * w3.z;
        float pw = a0 * w0.w + a1 * w1.w + a2 * w2.w + a3 * w3.w;

        #pragma unroll
        for (int m = 16; m > 0; m >>= 1) {   // width-32: stays inside this half
            px += __shfl_xor(px, m, 32);
            py += __shfl_xor(py, m, 32);
            pz += __shfl_xor(pz, m, 32);
            pw += __shfl_xor(pw, m, 32);
        }

        const float ah = (head == 0) ? __expf(px) :
                         (head == 1) ? __expf(py) :
                         (head == 2) ? __expf(pz) : __expf(pw);

        acc.x += ah * hs.x;
        acc.y += ah * hs.y;
        acc.z += ah * hs.z;
        acc.w += ah * hs.w;
        den   += ah;              // identical across the 8-lane head-group
    }

    // combine the two halves (same l => same features/head in both halves)
    acc.x += __shfl_xor(acc.x, 32, 64);
    acc.y += __shfl_xor(acc.y, 32, 64);
    acc.z += __shfl_xor(acc.z, 32, 64);
    acc.w += __shfl_xor(acc.w, 32, 64);
    den   += __shfl_xor(den,   32, 64);

    const float dinv = 1.0f / (den + 1e-9f);
    float4 o;
    o.x = acc.x * dinv + hd.x;
    o.y = acc.y * dinv + hd.y;
    o.z = acc.z * dinv + hd.z;
    o.w = acc.w * dinv + hd.w;

    // LayerNorm over 128 features (held by 32 distinct lanes; butterfly width 32)
    float s1 = o.x + o.y + o.z + o.w;
    float s2 = o.x * o.x + o.y * o.y + o.z * o.z + o.w * o.w;
    #pragma unroll
    for (int m = 16; m > 0; m >>= 1) {
        s1 += __shfl_xor(s1, m, 32);
        s2 += __shfl_xor(s2, m, 32);
    }
    const float mu   = s1 * (1.0f / 128.0f);
    const float var  = s2 * (1.0f / 128.0f) - mu * mu;
    const float rstd = rsqrtf(var + 1e-5f);

    if (half == 0) {
        const float4 g = ((const float4*)gamma)[l];
        const float4 b = ((const float4*)beta)[l];
        float4 res;
        res.x = (o.x - mu) * rstd * g.x + b.x;
        res.y = (o.y - mu) * rstd * g.y + b.y;
        res.z = (o.z - mu) * rstd * g.z + b.z;
        res.w = (o.w - mu) * rstd * g.w + b.w;
        ((float4*)(out + (size_t)node * DIM))[l] = res;
    }
}

// ---------------------------------------------------------------------------
extern "C" void kernel_launch(void* const* d_in, const int* in_sizes, int n_in,
                              void* d_out, int out_size, void* d_ws, size_t ws_size,
                              hipStream_t stream)
{
    const float* x     = (const float*)d_in[0];
    const int*   ei    = (const int*)d_in[1];
    const float* Wsrc  = (const float*)d_in[2];
    const float* Wdst  = (const float*)d_in[3];
    const float* Wattn = (const float*)d_in[4];
    const float* gamma = (const float*)d_in[5];
    const float* beta  = (const float*)d_in[6];
    float* out = (float*)d_out;

    const int n = in_sizes[0] / DIM;
    const int E = in_sizes[1] / 2;

    float* h_src = (float*)d_ws;                       // n*128 f32
    float* h_dst = h_src + (size_t)n * DIM;            // n*128 f32
    int*   deg    = (int*)(h_dst + (size_t)n * DIM);   // n
    int*   offs   = deg + n;                           // n+1
    int*   cursor = offs + n + 1;                      // n
    int*   srcs   = cursor + n;                        // E

    hipMemsetAsync(deg, 0, (size_t)n * sizeof(int), stream);

    k_hist   <<<(E + 255) / 256, 256, 0, stream>>>(ei, deg, E);
    k_scan   <<<1, 1024, 0, stream>>>(deg, offs, n);
    hipMemcpyAsync(cursor, offs, (size_t)n * sizeof(int),
                   hipMemcpyDeviceToDevice, stream);
    k_scatter<<<(E + 255) / 256, 256, 0, stream>>>(ei, cursor, srcs, E);

    k_dual_gemm<<<(n + 7) / 8, 256, 0, stream>>>(x, Wsrc, Wdst, h_src, h_dst, n);

    k_aggregate<<<(n + 3) / 4, 256, 0, stream>>>(
        offs, srcs, h_src, h_dst, Wattn, gamma, beta, out, n);
}

// Round 13
// 359.603 us; speedup vs baseline: 8.3708x; 1.2119x over previous
//
#include <hip/hip_runtime.h>
#include <math.h>

#define DIM 128
#define NHEADS 4

// ---------------------------------------------------------------------------
// K1: h_src = x @ W_src, h_dst = x @ W_dst   (fused; 8 x-rows per block)
// round-12: LDS reads vectorized to float4 (ds_read_b128 broadcast), j-step 4.
// unroll capped (round-4 lesson: full unroll -> VGPR=256 + 3.4 GB spill).
// ---------------------------------------------------------------------------
__global__ __launch_bounds__(256) void k_dual_gemm(
    const float* __restrict__ x,
    const float* __restrict__ Wsrc, const float* __restrict__ Wdst,
    float* __restrict__ h_src, float* __restrict__ h_dst, int n)
{
    __shared__ float xs[8][DIM];
    const int tid = threadIdx.x;
    const int r0 = blockIdx.x * 8;
    {
        int r  = tid >> 5;
        int c4 = tid & 31;
        int row = r0 + r;
        float4 v = make_float4(0.f, 0.f, 0.f, 0.f);
        if (row < n) v = ((const float4*)(x + (size_t)row * DIM))[c4];
        ((float4*)xs[r])[c4] = v;
    }
    __syncthreads();

    const int c = tid & 127;
    const float* __restrict__ W = (tid < 128) ? Wsrc : Wdst;
    float* __restrict__ H       = (tid < 128) ? h_src : h_dst;

    float acc[8] = {0.f, 0.f, 0.f, 0.f, 0.f, 0.f, 0.f, 0.f};
    #pragma unroll 2
    for (int j4 = 0; j4 < DIM / 4; ++j4) {
        const float w0 = W[(4 * j4 + 0) * DIM + c];
        const float w1 = W[(4 * j4 + 1) * DIM + c];
        const float w2 = W[(4 * j4 + 2) * DIM + c];
        const float w3 = W[(4 * j4 + 3) * DIM + c];
        #pragma unroll
        for (int r = 0; r < 8; ++r) {
            const float4 xv = ((const float4*)xs[r])[j4];   // b128 broadcast
            acc[r] += xv.x * w0 + xv.y * w1 + xv.z * w2 + xv.w * w3;
        }
    }
    #pragma unroll
    for (int r = 0; r < 8; ++r) {
        if (r0 + r < n) H[(size_t)(r0 + r) * DIM + c] = acc[r];
    }
}

// ---------------------------------------------------------------------------
// CSR build: histogram -> multi-block scan (A/B/C) -> scatter
// round-12: replaced 1-block serial-chunk scan (~1000 barriers on one CU)
// with standard 3-pass scan; pass C also writes cursor and offs[n].
// ---------------------------------------------------------------------------
__global__ __launch_bounds__(256) void k_hist(
    const int* __restrict__ ei, int* __restrict__ deg, int E)
{
    int e = blockIdx.x * 256 + threadIdx.x;
    if (e < E) atomicAdd(&deg[ei[E + e]], 1);
}

__global__ __launch_bounds__(1024) void k_scanA(
    const int* __restrict__ deg, int* __restrict__ exc,
    int* __restrict__ bsum, int n)
{
    __shared__ int buf[1024];
    const int t = threadIdx.x;
    const int i = blockIdx.x * 1024 + t;
    int v = (i < n) ? deg[i] : 0;
    buf[t] = v;
    __syncthreads();
    #pragma unroll
    for (int off = 1; off < 1024; off <<= 1) {
        int u = (t >= off) ? buf[t - off] : 0;
        __syncthreads();
        buf[t] += u;
        __syncthreads();
    }
    if (i < n) exc[i] = buf[t] - v;          // exclusive within block
    if (t == 1023) bsum[blockIdx.x] = buf[1023];
}

__global__ __launch_bounds__(1024) void k_scanB(int* __restrict__ bsum, int nb)
{
    __shared__ int buf[1024];
    const int t = threadIdx.x;
    int v = (t < nb) ? bsum[t] : 0;
    buf[t] = v;
    __syncthreads();
    #pragma unroll
    for (int off = 1; off < 1024; off <<= 1) {
        int u = (t >= off) ? buf[t - off] : 0;
        __syncthreads();
        buf[t] += u;
        __syncthreads();
    }
    if (t < nb) bsum[t] = buf[t] - v;        // exclusive block offsets
}

__global__ __launch_bounds__(256) void k_scanC(
    const int* __restrict__ exc, const int* __restrict__ bsum,
    int* __restrict__ offs, int* __restrict__ cursor, int n, int E)
{
    int i = blockIdx.x * 256 + threadIdx.x;
    if (i < n) {
        int o = exc[i] + bsum[i >> 10];
        offs[i] = o;
        cursor[i] = o;
    }
    if (i == 0) offs[n] = E;
}

__global__ __launch_bounds__(256) void k_scatter(
    const int* __restrict__ ei, int* __restrict__ cursor,
    int* __restrict__ srcs, int E)
{
    int e = blockIdx.x * 256 + threadIdx.x;
    if (e >= E) return;
    int s = ei[e];
    int d = ei[E + e];
    int pos = atomicAdd(&cursor[d], 1);
    srcs[pos] = s;
}

// ---------------------------------------------------------------------------
// K2: pull-mode aggregation + residual + LayerNorm. One wave (64 lanes) per
// node; the two 32-lane halves process alternating edges. Lane l (0..31)
// owns features 4l..4l+3 (float4). Every lane computes partials for ALL 4
// heads against full W_attn rows; width-32 butterfly -> full 128-feature
// alpha per head (width-8 variant was the round-11 absmax-0.5 bug).
// ---------------------------------------------------------------------------
__global__ __launch_bounds__(256) void k_aggregate(
    const int* __restrict__ offs, const int* __restrict__ srcs,
    const float* __restrict__ h_src, const float* __restrict__ h_dst,
    const float* __restrict__ W_attn,
    const float* __restrict__ gamma, const float* __restrict__ beta,
    float* __restrict__ out, int n)
{
    const int node = blockIdx.x * 4 + (threadIdx.x >> 6);
    if (node >= n) return;
    const int lane = threadIdx.x & 63;
    const int half = lane >> 5;       // 0: even edges, 1: odd edges
    const int l    = lane & 31;       // float4 index within the row
    const int head = l >> 3;          // head of features 4l..4l+3

    const float4 hd = ((const float4*)(h_dst + (size_t)node * DIM))[l];

    const float4 w0 = ((const float4*)W_attn)[4 * l + 0];
    const float4 w1 = ((const float4*)W_attn)[4 * l + 1];
    const float4 w2 = ((const float4*)W_attn)[4 * l + 2];
    const float4 w3 = ((const float4*)W_attn)[4 * l + 3];

    const int beg = offs[node];
    const int end = offs[node + 1];

    float4 acc = make_float4(0.f, 0.f, 0.f, 0.f);
    float  den = 0.f;

    for (int j = beg + half; j < end; j += 2) {
        const int s = srcs[j];
        const float4 hs = ((const float4*)(h_src + (size_t)s * DIM))[l];

        float a0 = hs.x + hd.x; a0 = a0 > 0.f ? a0 : 0.2f * a0;
        float a1 = hs.y + hd.y; a1 = a1 > 0.f ? a1 : 0.2f * a1;
        float a2 = hs.z + hd.z; a2 = a2 > 0.f ? a2 : 0.2f * a2;
        float a3 = hs.w + hd.w; a3 = a3 > 0.f ? a3 : 0.2f * a3;

        float px = a0 * w0.x + a1 * w1.x + a2 * w2.x + a3 * w3.x;
        float py = a0 * w0.y + a1 * w1.y + a2 * w2.y + a3 * w3.y;
        float pz = a0 * w0.z + a1 * w1.z + a2 * w2.z + a3 * w3.z;
        float pw = a0 * w0.w + a1 * w1.w + a2 * w2.w + a3 * w3.w;

        #pragma unroll
        for (int m = 16; m > 0; m >>= 1) {   // width-32: stays inside this half
            px += __shfl_xor(px, m, 32);
            py += __shfl_xor(py, m, 32);
            pz += __shfl_xor(pz, m, 32);
            pw += __shfl_xor(pw, m, 32);
        }

        const float ah = (head == 0) ? __expf(px) :
                         (head == 1) ? __expf(py) :
                         (head == 2) ? __expf(pz) : __expf(pw);

        acc.x += ah * hs.x;
        acc.y += ah * hs.y;
        acc.z += ah * hs.z;
        acc.w += ah * hs.w;
        den   += ah;              // identical across the 8-lane head-group
    }

    acc.x += __shfl_xor(acc.x, 32, 64);
    acc.y += __shfl_xor(acc.y, 32, 64);
    acc.z += __shfl_xor(acc.z, 32, 64);
    acc.w += __shfl_xor(acc.w, 32, 64);
    den   += __shfl_xor(den,   32, 64);

    const float dinv = 1.0f / (den + 1e-9f);
    float4 o;
    o.x = acc.x * dinv + hd.x;
    o.y = acc.y * dinv + hd.y;
    o.z = acc.z * dinv + hd.z;
    o.w = acc.w * dinv + hd.w;

    float s1 = o.x + o.y + o.z + o.w;
    float s2 = o.x * o.x + o.y * o.y + o.z * o.z + o.w * o.w;
    #pragma unroll
    for (int m = 16; m > 0; m >>= 1) {
        s1 += __shfl_xor(s1, m, 32);
        s2 += __shfl_xor(s2, m, 32);
    }
    const float mu   = s1 * (1.0f / 128.0f);
    const float var  = s2 * (1.0f / 128.0f) - mu * mu;
    const float rstd = rsqrtf(var + 1e-5f);

    if (half == 0) {
        const float4 g = ((const float4*)gamma)[l];
        const float4 b = ((const float4*)beta)[l];
        float4 res;
        res.x = (o.x - mu) * rstd * g.x + b.x;
        res.y = (o.y - mu) * rstd * g.y + b.y;
        res.z = (o.z - mu) * rstd * g.z + b.z;
        res.w = (o.w - mu) * rstd * g.w + b.w;
        ((float4*)(out + (size_t)node * DIM))[l] = res;
    }
}

// ---------------------------------------------------------------------------
extern "C" void kernel_launch(void* const* d_in, const int* in_sizes, int n_in,
                              void* d_out, int out_size, void* d_ws, size_t ws_size,
                              hipStream_t stream)
{
    const float* x     = (const float*)d_in[0];
    const int*   ei    = (const int*)d_in[1];
    const float* Wsrc  = (const float*)d_in[2];
    const float* Wdst  = (const float*)d_in[3];
    const float* Wattn = (const float*)d_in[4];
    const float* gamma = (const float*)d_in[5];
    const float* beta  = (const float*)d_in[6];
    float* out = (float*)d_out;

    const int n = in_sizes[0] / DIM;
    const int E = in_sizes[1] / 2;
    const int nb = (n + 1023) / 1024;          // scan blocks (49 for n=50K)

    float* h_src = (float*)d_ws;                       // n*128 f32
    float* h_dst = h_src + (size_t)n * DIM;            // n*128 f32
    int*   deg    = (int*)(h_dst + (size_t)n * DIM);   // n
    int*   offs   = deg + n;                           // n+1
    int*   cursor = offs + n + 1;                      // n
    int*   srcs   = cursor + n;                        // E
    int*   exc    = srcs + E;                          // n
    int*   bsum   = exc + n;                           // nb

    hipMemsetAsync(deg, 0, (size_t)n * sizeof(int), stream);

    k_hist <<<(E + 255) / 256, 256, 0, stream>>>(ei, deg, E);
    k_scanA<<<nb, 1024, 0, stream>>>(deg, exc, bsum, n);
    k_scanB<<<1, 1024, 0, stream>>>(bsum, nb);
    k_scanC<<<(n + 255) / 256, 256, 0, stream>>>(exc, bsum, offs, cursor, n, E);
    k_scatter<<<(E + 255) / 256, 256, 0, stream>>>(ei, cursor, srcs, E);

    k_dual_gemm<<<(n + 7) / 8, 256, 0, stream>>>(x, Wsrc, Wdst, h_src, h_dst, n);

    k_aggregate<<<(n + 3) / 4, 256, 0, stream>>>(
        offs, srcs, h_src, h_dst, Wattn, gamma, beta, out, n);
}